// Round 11
// baseline (15510.829 us; speedup 1.0000x reference)
//
#include <hip/hip_runtime.h>
#include <math.h>

#define NN 4096
#define KK 8
#define DD 512
#define HH 512
#define NB 256
#define TPB 1024
#define NXCD 8
#define MAXT 4096                 // max ticks
#define ENTCAP 40960              // sum(L_i) <= 36864 plus per-tick pad
#define ENCCAP 16384              // NN + per-tick pad
#define NNHH ((size_t)NN * HH)

typedef float v2f __attribute__((ext_vector_type(2)));

// ws layout (bytes) — R9's proven layout
#define OFF_CTRL 0                            // barrier lines (zeroed each launch)
#define OFF_HDR  8192                         // int nticks
#define OFF_TCNT (OFF_HDR + 256)              // int gcnt[MAXT]
#define OFF_TOFF (OFF_TCNT + 4 * MAXT)        // int goff[MAXT]
#define OFF_TCUR (OFF_TOFF + 4 * MAXT)        // int gcur[MAXT]
#define OFF_ECNT (OFF_TCUR + 4 * MAXT)        // int gecnt[MAXT]
#define OFF_EOFF (OFF_ECNT + 4 * MAXT)        // int geoff[MAXT]
#define OFF_ECUR (OFF_EOFF + 4 * MAXT)        // int gecur[MAXT]
#define OFF_LIST (OFF_ECUR + 4 * MAXT)        // int list[ENTCAP]: i|q<<12|ll<<16|lr<<20
#define OFF_XL   (OFF_LIST + 4 * ENTCAP)      // int xl[ENTCAP]
#define OFF_XR   (OFF_XL + 4 * ENTCAP)        // int xr[ENTCAP]
#define OFF_ENC  (OFF_XR + 4 * ENTCAP)        // int enc[ENCCAP]: i|ll<<12|lr<<16
#define OFF_H    (OFF_ENC + 4 * ENCCAP)       // float hbuf[2][2][NN][HH]
#define OFF_C    (OFF_H + 4 * 2 * 2 * NN * HH)    // float cbuf[2][NN][HH]
#define WS_ZERO_BYTES 8192

// tanh(x) = 1 - 2/(exp(2x)+1)  — saturates correctly at +/-inf, ~1e-6 abs err
__device__ __forceinline__ float fast_tanh2x(float two_x) {
    return 1.0f - 2.0f * __builtin_amdgcn_rcpf(__expf(two_x) + 1.0f);
}

// async global->LDS, 16B/lane — CACHED path (x0 immutable; ctx write-once:
// written exactly once via write-through store, read only at strictly later
// ticks, 2KB-aligned rows, dispatch-start caches clean. R6..R9-proven.)
__device__ __forceinline__ void glds16(const float* g, float* l) {
    typedef __attribute__((address_space(1))) const void GV;
    typedef __attribute__((address_space(3))) void LV;
    __builtin_amdgcn_global_load_lds((GV*)g, (LV*)l, 16, 0, 0);
}

// ---------------------------------------------------------------------------
// Memory model (R4..R9-proven):
//   h, c, ctx: agent-relaxed atomic STORE (write-through, MALL-visible once
//     vmcnt drains at the pre-barrier __syncthreads) + agent-relaxed atomic
//     LOAD (bypasses stale L1/L2). No fences anywhere.
//   x0, ctx(read), list/xl/xr/enc, weights: plain cached loads, stay hot.
//   cp (prev c) staged through LDS per block-contiguous 16-unit segment (R8).
// ---------------------------------------------------------------------------
__device__ __forceinline__ void coh_store(float* p, float v) {
    __hip_atomic_store(p, v, __ATOMIC_RELAXED, __HIP_MEMORY_SCOPE_AGENT);
}
__device__ __forceinline__ v2f ldb2(const float* p) {
    unsigned long long raw = __hip_atomic_load((const unsigned long long*)p,
                                               __ATOMIC_RELAXED, __HIP_MEMORY_SCOPE_AGENT);
    union { unsigned long long u; v2f f; } c; c.u = raw; return c.f;
}

// ---------------------------------------------------------------------------
// Prologue (single block): ASAP tick schedule with per-position read slack.
// Verbatim from PASSING R9.
// ---------------------------------------------------------------------------
__global__ void __launch_bounds__(1024)
sched_kernel(const int* __restrict__ lch, const int* __restrict__ rch, char* ws) {
    const int t = threadIdx.x;
    int* hdr   = (int*)(ws + OFF_HDR);
    int* gcnt  = (int*)(ws + OFF_TCNT);
    int* goff  = (int*)(ws + OFF_TOFF);
    int* gcur  = (int*)(ws + OFF_TCUR);
    int* gecnt = (int*)(ws + OFF_ECNT);
    int* geoff = (int*)(ws + OFF_EOFF);
    int* gecur = (int*)(ws + OFF_ECUR);
    int* list  = (int*)(ws + OFF_LIST);
    int* xl    = (int*)(ws + OFF_XL);
    int* xr    = (int*)(ws + OFF_XR);
    int* enc   = (int*)(ws + OFF_ENC);

    __shared__ int s_meta[NN];     // ll | lr<<4 | L<<8
    __shared__ int s_start[NN];
    __shared__ int s_seg[1024];
    __shared__ int s_un, s_nt;

    for (int j = t; j < MAXT; j += 1024) { gcnt[j] = 0; gcur[j] = 0; gecnt[j] = 0; gecur[j] = 0; }
    if (t == 0) s_nt = 0;
    for (int i = t; i < NN; i += 1024) {
        int ll = 1, lr = 1; bool has = false;
#pragma unroll
        for (int k = 0; k < KK; ++k) {
            if (lch[i * KK + k] >= 0) { ll = k + 2; has = true; }
            if (rch[i * KK + k] >= 0) { lr = k + 2; has = true; }
        }
        const int L = ll > lr ? ll : lr;
        s_meta[i]  = ll | (lr << 4) | (L << 8);
        s_start[i] = has ? -1 : 0;
    }
    __syncthreads();

    // fixpoint: start_j = max(0, max over child occ (c,k): start_c + L_c - k)
    for (;;) {
        if (t == 0) s_un = 0;
        __syncthreads();
        int myUn = 0;
        for (int i = t; i < NN; i += 1024) {
            if (s_start[i] < 0) {
                int mx = 0; bool ok = true;
#pragma unroll
                for (int k = 0; k < KK; ++k) {
                    int c = lch[i * KK + k];
                    if (c >= 0) {
                        const int st = s_start[c];
                        if (st < 0) ok = false;
                        else { const int v = st + ((s_meta[c] >> 8) & 0xF) - k; if (v > mx) mx = v; }
                    }
                    c = rch[i * KK + k];
                    if (c >= 0) {
                        const int st = s_start[c];
                        if (st < 0) ok = false;
                        else { const int v = st + ((s_meta[c] >> 8) & 0xF) - k; if (v > mx) mx = v; }
                    }
                }
                if (ok) s_start[i] = mx; else ++myUn;
            }
        }
        if (myUn) atomicAdd(&s_un, myUn);
        __syncthreads();
        if (s_un == 0) break;
        __syncthreads();
    }

    for (int i = t; i < NN; i += 1024)
        atomicMax(&s_nt, s_start[i] + ((s_meta[i] >> 8) & 0xF) + 1);
    __syncthreads();
    const int nt = s_nt;
    if (t == 0) hdr[0] = nt;
    for (int i = t; i < NN; i += 1024) {
        const int s = s_start[i], L = (s_meta[i] >> 8) & 0xF;
        for (int q = 0; q < L; ++q) atomicAdd(&gcnt[s + q], 1);
        atomicAdd(&gecnt[s + L], 1);
    }
    __syncthreads();

    auto scan4 = [&](int* cnt, int* off) {
        const int per = (nt + 1023) >> 10;
        const int lo = t * per, hi = (lo + per < nt) ? lo + per : nt;
        int sum = 0;
        for (int j = lo; j < hi; ++j) sum += (cnt[j] + 3) & ~3;
        s_seg[t] = sum;
        __syncthreads();
        if (t == 0) { int run = 0; for (int k = 0; k < 1024; ++k) { const int v = s_seg[k]; s_seg[k] = run; run += v; } }
        __syncthreads();
        int run = s_seg[t];
        for (int j = lo; j < hi; ++j) { off[j] = run; run += (cnt[j] + 3) & ~3; }
        __syncthreads();
    };
    scan4(gcnt, goff);
    scan4(gecnt, geoff);

    for (int i = t; i < NN; i += 1024) {
        const int m = s_meta[i], s = s_start[i];
        const int ll = m & 0xF, lr = (m >> 4) & 0xF, L = (m >> 8) & 0xF;
        for (int q = 0; q < L; ++q) {
            const int pos = goff[s + q] + atomicAdd(&gcur[s + q], 1);
            list[pos] = i | (q << 12) | (ll << 16) | (lr << 20);
            xl[pos] = (q == 0) ? i : ((q < ll) ? lch[i * KK + q - 1] : -1);
            xr[pos] = (q == 0) ? i : ((q < lr) ? rch[i * KK + q - 1] : -1);
        }
        const int ep = geoff[s + L] + atomicAdd(&gecur[s + L], 1);
        enc[ep] = i | (ll << 12) | (lr << 16);
    }
}

// ---------------------------------------------------------------------------
// Grid barrier (R4/R6..R9-proven): leader-gather + XCD-fanout, flags only,
// relaxed agent scope, no fences, poll backoff. SAFE ONLY at <=256 blocks,
// 1 block/CU. UNCHANGED from R9 (R10's per-node flags regressed: h is spread
// over 32 blocks, so every hop needs 32-block convergence anyway — per-entry
// polls just re-pay the barrier cost with more MALL traffic).
// ---------------------------------------------------------------------------
__device__ __forceinline__ void grid_barrier(int* ctrl, int blk, int xcd, int target) {
    __syncthreads();   // every wave: s_waitcnt vmcnt(0) before s_barrier
    if (blk == 0) {
        const int t = threadIdx.x;
        if (t < 64) {
            if (t == 0)
                __hip_atomic_store(ctrl + 0, target, __ATOMIC_RELAXED, __HIP_MEMORY_SCOPE_AGENT);
            int spin = 0;
            for (;;) {
                const int m0 = __hip_atomic_load(ctrl + t * 4 + 0, __ATOMIC_RELAXED, __HIP_MEMORY_SCOPE_AGENT);
                const int m1 = __hip_atomic_load(ctrl + t * 4 + 1, __ATOMIC_RELAXED, __HIP_MEMORY_SCOPE_AGENT);
                const int m2 = __hip_atomic_load(ctrl + t * 4 + 2, __ATOMIC_RELAXED, __HIP_MEMORY_SCOPE_AGENT);
                const int m3 = __hip_atomic_load(ctrl + t * 4 + 3, __ATOMIC_RELAXED, __HIP_MEMORY_SCOPE_AGENT);
                const bool ok = (m0 >= target) & (m1 >= target) & (m2 >= target) & (m3 >= target);
                if (__all(ok)) break;
                if (++spin > 64) __builtin_amdgcn_s_sleep(16);
                else             __builtin_amdgcn_s_sleep(1);
            }
            if (t < NXCD)
                __hip_atomic_store(ctrl + 512 + t * 16, target, __ATOMIC_RELAXED, __HIP_MEMORY_SCOPE_AGENT);
        }
    } else {
        if (threadIdx.x == 0) {
            __hip_atomic_store(ctrl + blk, target, __ATOMIC_RELAXED, __HIP_MEMORY_SCOPE_AGENT);
            int spin = 0;
            while (__hip_atomic_load(ctrl + 512 + xcd * 16, __ATOMIC_RELAXED, __HIP_MEMORY_SCOPE_AGENT) < target) {
                if (++spin > 64) __builtin_amdgcn_s_sleep(16);
                else             __builtin_amdgcn_s_sleep(1);
            }
        }
    }
    __syncthreads();
}

// R11 = R9 + enc/substep OVERLAP (the single change this round):
//   enc(t) is independent of tick-t substeps — it reads h written at ticks
//   <= t-1 (covered by barrier t-1) and its ctx is consumed no earlier than
//   t+1 (scheduler invariant read >= enc+1). So each wave-group's FIRST enc
//   slot is preloaded at tick start (8x ldb2 -> 16 VGPR) in parallel with
//   substep h-staging, and finished (reduce + ctx store) after the substep
//   chunks. Rare extra slots (ecnt > 8) processed serially as before.
//   VGPR 64 -> ~80-96 (cap 128 at 4 waves/SIMD — no spill expected; spill
//   signature would be FETCH/WRITE explosion).
__global__ void __launch_bounds__(TPB, 1)
tree_lstm_kernel(const float* __restrict__ x0,
                 const float* __restrict__ Wl_ih, const float* __restrict__ Wl_hh,
                 const float* __restrict__ bl_ih, const float* __restrict__ bl_hh,
                 const float* __restrict__ Wr_ih, const float* __restrict__ Wr_hh,
                 const float* __restrict__ br_ih, const float* __restrict__ br_hh,
                 const float* __restrict__ W_enc, const float* __restrict__ b_enc,
                 float* ctx, char* ws) {
    const int tid  = threadIdx.x;
    const int wv   = tid >> 6;                 // wave index within block, 0..15
    const int wave = (blockIdx.x * TPB + tid) >> 6;  // 0..4095
    const int lane = tid & 63;
    const int u    = wave & 511;        // hidden unit owned by this wave
    const int side = (wave >> 9) & 1;   // 0 = left chain, 1 = right chain
    const int p    = (wave >> 10) & 3;  // 4-way slot split (uniform per block)
    const int egrp = (wave >> 9) & 7;   // enc: 8-way slot split
    const int xcd  = blockIdx.x & (NXCD - 1);
    const int u0b  = (blockIdx.x * 16) & 511;  // block's first unit (16 contiguous)

    int*   ctrl  = (int*)(ws + OFF_CTRL);
    int*   hdr   = (int*)(ws + OFF_HDR);
    int*   gcnt  = (int*)(ws + OFF_TCNT);
    int*   goff  = (int*)(ws + OFF_TOFF);
    int*   gecnt = (int*)(ws + OFF_ECNT);
    int*   geoff = (int*)(ws + OFF_EOFF);
    int*   list  = (int*)(ws + OFF_LIST);
    int*   xlidx = (int*)(ws + OFF_XL);
    int*   xridx = (int*)(ws + OFF_XR);
    int*   encl  = (int*)(ws + OFF_ENC);
    float* hbuf  = (float*)(ws + OFF_H);
    float* cbuf  = (float*)(ws + OFF_C);

    // double-buffered row staging (x cached->LDS, h/c bypass->reg->LDS) + pad
    __shared__ float s_x[2][8][512];
    __shared__ float s_h[2][8][512];
    __shared__ float s_c[2][8][16];
    __shared__ float s_pad[5120];   // -> ~87KB total: 1 block/CU guaranteed

    const float* Wih = side ? Wr_ih : Wl_ih;
    const float* Whh = side ? Wr_hh : Wl_hh;
    const float* bih = side ? br_ih : bl_ih;
    const float* bhh = side ? br_hh : bl_hh;

    // Wave-resident weights: 4 gate rows; lane l covers dims {4l..4l+3} and
    // {256+4l..256+4l+3} (dense 16B slices matching the LDS staging layout).
    v2f wih2[4][4], whh2[4][4];
#pragma unroll
    for (int g = 0; g < 4; ++g) {
        const size_t row = (size_t)g * HH + u;
        const float4 wa = *(const float4*)(Wih + row * DD + lane * 4);
        const float4 wb = *(const float4*)(Wih + row * DD + 256 + lane * 4);
        wih2[g][0] = (v2f){wa.x, wa.y}; wih2[g][1] = (v2f){wa.z, wa.w};
        wih2[g][2] = (v2f){wb.x, wb.y}; wih2[g][3] = (v2f){wb.z, wb.w};
        const float4 ha = *(const float4*)(Whh + row * HH + lane * 4);
        const float4 hb = *(const float4*)(Whh + row * HH + 256 + lane * 4);
        whh2[g][0] = (v2f){ha.x, ha.y}; whh2[g][1] = (v2f){ha.z, ha.w};
        whh2[g][2] = (v2f){hb.x, hb.y}; whh2[g][3] = (v2f){hb.z, hb.w};
    }
    const float bsumL = bih[(size_t)(lane & 3) * HH + u] + bhh[(size_t)(lane & 3) * HH + u];
    v2f wenc2[8];
#pragma unroll
    for (int j = 0; j < 4; ++j) {
        const float4 t = *(const float4*)(W_enc + (size_t)u * (2 * HH) + lane * 16 + j * 4);
        wenc2[j * 2 + 0] = (v2f){t.x, t.y};
        wenc2[j * 2 + 1] = (v2f){t.z, t.w};
    }
    const float bencv = b_enc[u];

    float* cb = cbuf + (size_t)side * NNHH;
    const int* xq = side ? xridx : xlidx;
    const int nt = hdr[0];
    if (nt < 0) ((volatile float*)s_pad)[tid] = 0.f;  // keep pad alive
    int bnum = 0;

    const int lhalf = lane >> 5;
    const int col   = (lane * 16) & 511;

    for (int tk = 0; tk < nt; ++tk) {
        const int cnt  = gcnt[tk],  off  = goff[tk];
        const int ecnt = gecnt[tk], eoff = geoff[tk];
        const int limit = off + cnt;
        const int elim  = eoff + ecnt;

        // ---- enc PRELOAD (slot0 of this wave-group): issue at tick start so
        // the uncached h-reads overlap the substep staging below ----
        v2f  eh[8];
        bool eact = false;
        int  enode = 0;
        if (ecnt > 0) {
            const int slot0 = eoff + egrp;
            if (slot0 < elim) {
                const int e   = encl[slot0];
                enode = e & 0xFFF;
                const int len = (e >> (12 + 4 * lhalf)) & 0xF;
                const float* hv = hbuf + (size_t)(((len - 1) & 1) * 2 + lhalf) * NNHH
                                + (size_t)enode * HH + col;
#pragma unroll
                for (int k = 0; k < 8; ++k)
                    eh[k] = ldb2(hv + k * 2);
                eact = true;
            }
        }

        // slot p owns positions {slotBase + 32c + j, j in [0,8)}
        const int slotBase = off + p * 8;
        const int nch = (limit > slotBase) ? ((limit - slotBase + 31) >> 5) : 0;

        // staging (waves 0-7): x rows cached glds16 -> LDS; h rows ldb2 ->
        // regs; c-segment on lanes 0-7. issue-early / write-late (R8-proven).
        v2f ph0, ph1, ph2, ph3, pc;
        bool pact = false;

        auto issue = [&](int buf, int chS) {
            pact = false;
            if (wv < 8) {
                const int e = chS + wv;
                if (e < limit) {
                    const int ent  = list[e];
                    const int q    = (ent >> 12) & 0xF;
                    const int xsrc = xq[e];
                    if (xsrc >= 0) {
                        const float* xrow = ((q == 0) ? x0 : ctx) + (size_t)xsrc * DD + lane * 4;
                        glds16(xrow,       &s_x[buf][wv][0]);
                        glds16(xrow + 256, &s_x[buf][wv][256]);
                        if (q > 0) {
                            pact = true;
                            const int i = ent & 0xFFF;
                            const float* hr = hbuf + (size_t)(((q & 1) ^ 1) * 2 + side) * NNHH
                                            + (size_t)i * HH + lane * 4;
                            ph0 = ldb2(hr);       ph1 = ldb2(hr + 2);
                            ph2 = ldb2(hr + 256); ph3 = ldb2(hr + 258);
                            if (lane < 8)
                                pc = ldb2(cb + (size_t)i * HH + u0b + lane * 2);
                        }
                    }
                }
            }
        };
        auto writeb = [&](int buf) {
            if (pact) {
                *(v2f*)&s_h[buf][wv][lane * 4]       = ph0;
                *(v2f*)&s_h[buf][wv][lane * 4 + 2]   = ph1;
                *(v2f*)&s_h[buf][wv][lane * 4 + 256] = ph2;
                *(v2f*)&s_h[buf][wv][lane * 4 + 258] = ph3;
                if (lane < 8)
                    *(v2f*)&s_c[buf][wv][lane * 2] = pc;
            }
        };

        if (nch > 0) { issue(0, slotBase); writeb(0); }
        for (int c = 0; c < nch; ++c) {
            __syncthreads();                    // buf[c&1] staged (all waves)
            const int chS = slotBase + (c << 5);
            if (c + 1 < nch) issue((c + 1) & 1, chS + 32);
            const int bb = c & 1;

            const int4 eA = *(const int4*)(list + chS);
            const int4 eB = *(const int4*)(list + chS + 4);
            const int4 cA = *(const int4*)(xq + chS);
            const int4 cB = *(const int4*)(xq + chS + 4);
            const int ei[8] = {eA.x, eA.y, eA.z, eA.w, eB.x, eB.y, eB.z, eB.w};
            const int ci[8] = {cA.x, cA.y, cA.z, cA.w, cB.x, cB.y, cB.z, cB.w};
            bool act[8];
#pragma unroll
            for (int j = 0; j < 8; ++j)
                act[j] = (chS + j < limit) && (ci[j] >= 0);

#pragma unroll
            for (int j = 0; j < 8; ++j) {
                if (!act[j]) continue;
                const int ent = ei[j];
                const int i   = ent & 0xFFF;
                const int qj  = (ent >> 12) & 0xF;
                const float cpj = (qj > 0) ? s_c[bb][j][wv] : 0.f;  // LDS broadcast
                const float4 xa = *(const float4*)&s_x[bb][j][lane * 4];
                const float4 xc = *(const float4*)&s_x[bb][j][lane * 4 + 256];
                v2f xv0 = (v2f){xa.x, xa.y}, xv1 = (v2f){xa.z, xa.w};
                v2f xv2 = (v2f){xc.x, xc.y}, xv3 = (v2f){xc.z, xc.w};
                v2f A0 = wih2[0][0] * xv0 + wih2[0][1] * xv1 + wih2[0][2] * xv2 + wih2[0][3] * xv3;
                v2f A1 = wih2[1][0] * xv0 + wih2[1][1] * xv1 + wih2[1][2] * xv2 + wih2[1][3] * xv3;
                v2f A2 = wih2[2][0] * xv0 + wih2[2][1] * xv1 + wih2[2][2] * xv2 + wih2[2][3] * xv3;
                v2f A3 = wih2[3][0] * xv0 + wih2[3][1] * xv1 + wih2[3][2] * xv2 + wih2[3][3] * xv3;
                if (qj > 0) {
                    const float4 ha = *(const float4*)&s_h[bb][j][lane * 4];
                    const float4 hc = *(const float4*)&s_h[bb][j][lane * 4 + 256];
                    v2f hv0 = (v2f){ha.x, ha.y}, hv1 = (v2f){ha.z, ha.w};
                    v2f hv2 = (v2f){hc.x, hc.y}, hv3 = (v2f){hc.z, hc.w};
                    A0 += whh2[0][0] * hv0 + whh2[0][1] * hv1 + whh2[0][2] * hv2 + whh2[0][3] * hv3;
                    A1 += whh2[1][0] * hv0 + whh2[1][1] * hv1 + whh2[1][2] * hv2 + whh2[1][3] * hv3;
                    A2 += whh2[2][0] * hv0 + whh2[2][1] * hv1 + whh2[2][2] * hv2 + whh2[2][3] * hv3;
                    A3 += whh2[3][0] * hv0 + whh2[3][1] * hv1 + whh2[3][2] * hv2 + whh2[3][3] * hv3;
                }
                float a0 = A0[0] + A0[1], a1 = A1[0] + A1[1];
                float a2 = A2[0] + A2[1], a3 = A3[0] + A3[1];
                // merge butterfly: lane l ends holding gate (l&3)'s sum
                float v01, v23, v;
                {
                    const bool hi = lane & 1;
                    float keep = hi ? a1 : a0, send = hi ? a0 : a1;
                    v01 = keep + __shfl_xor(send, 1, 64);
                    keep = hi ? a3 : a2; send = hi ? a2 : a3;
                    v23 = keep + __shfl_xor(send, 1, 64);
                }
                {
                    const bool hi = lane & 2;
                    const float keep = hi ? v23 : v01, send = hi ? v01 : v23;
                    v = keep + __shfl_xor(send, 2, 64);
                }
                v += __shfl_xor(v, 4, 64);
                v += __shfl_xor(v, 8, 64);
                v += __shfl_xor(v, 16, 64);
                v += __shfl_xor(v, 32, 64);
                // wave-parallel nonlinearities: sigm(x)=(tanh(x/2)+1)/2
                const float gate = v + bsumL;
                const bool  isG  = (lane & 3) == 2;
                const float th   = fast_tanh2x(isG ? (gate + gate) : gate);
                const float tl   = isG ? th : 0.5f * (th + 1.0f);
                const float ti = __shfl(tl, 0, 64);
                const float tf = __shfl(tl, 1, 64);
                const float tg = __shfl(tl, 2, 64);
                const float to = __shfl(tl, 3, 64);
                const float cn = tf * cpj + ti * tg;
                const float hn = to * fast_tanh2x(cn + cn);
                if (lane == 0) {
                    coh_store(cb + (size_t)i * HH + u, cn);
                    coh_store(hbuf + (size_t)((qj & 1) * 2 + side) * NNHH + (size_t)i * HH + u, hn);
                }
            }
            if (c + 1 < nch) writeb((c + 1) & 1);   // waits loads, LDS write
        }

        // ---- enc FINISH: preloaded slot0, then any extra slots serially ----
        if (ecnt > 0) {
            if (eact) {
                v2f acc2 = {0.f, 0.f};
#pragma unroll
                for (int k = 0; k < 8; ++k)
                    acc2 += wenc2[k] * eh[k];
                float acc = acc2[0] + acc2[1];
#pragma unroll
                for (int m = 1; m < 64; m <<= 1) acc += __shfl_xor(acc, m, 64);
                if (lane == 0)
                    coh_store(&ctx[(size_t)enode * DD + u], fast_tanh2x(2.0f * (acc + bencv)));
            }
            for (int slot = eoff + egrp + 8; slot < elim; slot += 8) {
                const int e   = encl[slot];
                const int i   = e & 0xFFF;
                const int len = (e >> (12 + 4 * lhalf)) & 0xF;
                const float* hv = hbuf + (size_t)(((len - 1) & 1) * 2 + lhalf) * NNHH
                                + (size_t)i * HH + col;
                v2f acc2 = {0.f, 0.f};
#pragma unroll
                for (int k = 0; k < 8; ++k)
                    acc2 += wenc2[k] * ldb2(hv + k * 2);
                float acc = acc2[0] + acc2[1];
#pragma unroll
                for (int m = 1; m < 64; m <<= 1) acc += __shfl_xor(acc, m, 64);
                if (lane == 0)
                    coh_store(&ctx[(size_t)i * DD + u], fast_tanh2x(2.0f * (acc + bencv)));
            }
        }
        grid_barrier(ctrl, blockIdx.x, xcd, ++bnum);
    }
}

extern "C" void kernel_launch(void* const* d_in, const int* in_sizes, int n_in,
                              void* d_out, int out_size, void* d_ws, size_t ws_size,
                              hipStream_t stream) {
    hipMemsetAsync(d_ws, 0, WS_ZERO_BYTES, stream);
    sched_kernel<<<dim3(1), dim3(1024), 0, stream>>>(
        (const int*)d_in[11], (const int*)d_in[12], (char*)d_ws);
    tree_lstm_kernel<<<dim3(NB), dim3(TPB), 0, stream>>>(
        (const float*)d_in[0],
        (const float*)d_in[1], (const float*)d_in[2],
        (const float*)d_in[3], (const float*)d_in[4],
        (const float*)d_in[5], (const float*)d_in[6],
        (const float*)d_in[7], (const float*)d_in[8],
        (const float*)d_in[9], (const float*)d_in[10],
        (float*)d_out, (char*)d_ws);
}

// Round 12
// 13077.069 us; speedup vs baseline: 1.1861x; 1.1861x over previous
//
#include <hip/hip_runtime.h>
#include <math.h>

#define NN 4096
#define KK 8
#define DD 512
#define HH 512
#define NB 256
#define TPB 1024
#define NXCD 8
#define MAXT 4096                 // max ticks
#define ENTCAP 40960              // sum(L_i) <= 36864 plus per-tick pad
#define ENCCAP 16384              // NN + per-tick pad
#define NNHH ((size_t)NN * HH)

typedef float v2f __attribute__((ext_vector_type(2)));

// ws layout (bytes) — R9's proven layout (NO new buffers: hfin aliases cbuf)
#define OFF_CTRL 0                            // barrier lines (zeroed each launch)
#define OFF_HDR  8192                         // int nticks
#define OFF_TCNT (OFF_HDR + 256)              // int gcnt[MAXT]
#define OFF_TOFF (OFF_TCNT + 4 * MAXT)        // int goff[MAXT]
#define OFF_TCUR (OFF_TOFF + 4 * MAXT)        // int gcur[MAXT]
#define OFF_ECNT (OFF_TCUR + 4 * MAXT)        // int gecnt[MAXT]
#define OFF_EOFF (OFF_ECNT + 4 * MAXT)        // int geoff[MAXT]
#define OFF_ECUR (OFF_EOFF + 4 * MAXT)        // int gecur[MAXT]
#define OFF_LIST (OFF_ECUR + 4 * MAXT)        // int list[ENTCAP]: i|q<<12|ll<<16|lr<<20
#define OFF_XL   (OFF_LIST + 4 * ENTCAP)      // int xl[ENTCAP]
#define OFF_XR   (OFF_XL + 4 * ENTCAP)        // int xr[ENTCAP]
#define OFF_ENC  (OFF_XR + 4 * ENTCAP)        // int enc[ENCCAP]: i|ll<<12|lr<<16
#define OFF_H    (OFF_ENC + 4 * ENCCAP)       // float hbuf[2][2][NN][HH]
#define OFF_C    (OFF_H + 4 * 2 * 2 * NN * HH)    // float cbuf[2][NN][HH]
#define WS_ZERO_BYTES 8192

// tanh(x) = 1 - 2/(exp(2x)+1)  — saturates correctly at +/-inf, ~1e-6 abs err
__device__ __forceinline__ float fast_tanh2x(float two_x) {
    return 1.0f - 2.0f * __builtin_amdgcn_rcpf(__expf(two_x) + 1.0f);
}

// async global->LDS, 16B/lane — CACHED path. Used for x0 (immutable), ctx
// (write-once) and — NEW in R12 — cbuf-as-final-h (write-once after the
// node's chain ends: the final substep stores hn there and c is dead; first
// read is strictly after the barrier that covers that store; bypass loads
// never fill L2 and write-through stores can't leave stale copies, so a
// plain cached read cannot observe a stale line. Same proof as ctx, R6/R9.)
__device__ __forceinline__ void glds16(const float* g, float* l) {
    typedef __attribute__((address_space(1))) const void GV;
    typedef __attribute__((address_space(3))) void LV;
    __builtin_amdgcn_global_load_lds((GV*)g, (LV*)l, 16, 0, 0);
}

// ---------------------------------------------------------------------------
// Memory model (R4..R9-proven):
//   h, c, ctx: agent-relaxed atomic STORE (write-through, MALL-visible once
//     vmcnt drains at the pre-barrier __syncthreads) + agent-relaxed atomic
//     LOAD (bypasses stale L1/L2). No fences anywhere.
//   x0, ctx(read), final-h(read, write-once), list/xl/xr/enc, weights:
//     plain cached loads, stay hot.
//   cp (prev c) staged through LDS per block-contiguous 16-unit segment (R8).
// R11 LESSON (spill): compiler pins VGPR=64 at this occupancy; long-lived
//   register arrays spill to scratch (WRITE_SIZE 1.45->4.4GB). All preloads
//   must go to LDS via glds16 — zero register pressure.
// ---------------------------------------------------------------------------
__device__ __forceinline__ void coh_store(float* p, float v) {
    __hip_atomic_store(p, v, __ATOMIC_RELAXED, __HIP_MEMORY_SCOPE_AGENT);
}
__device__ __forceinline__ v2f ldb2(const float* p) {
    unsigned long long raw = __hip_atomic_load((const unsigned long long*)p,
                                               __ATOMIC_RELAXED, __HIP_MEMORY_SCOPE_AGENT);
    union { unsigned long long u; v2f f; } c; c.u = raw; return c.f;
}

// ---------------------------------------------------------------------------
// Prologue (single block): ASAP tick schedule with per-position read slack.
// Verbatim from PASSING R9.
// ---------------------------------------------------------------------------
__global__ void __launch_bounds__(1024)
sched_kernel(const int* __restrict__ lch, const int* __restrict__ rch, char* ws) {
    const int t = threadIdx.x;
    int* hdr   = (int*)(ws + OFF_HDR);
    int* gcnt  = (int*)(ws + OFF_TCNT);
    int* goff  = (int*)(ws + OFF_TOFF);
    int* gcur  = (int*)(ws + OFF_TCUR);
    int* gecnt = (int*)(ws + OFF_ECNT);
    int* geoff = (int*)(ws + OFF_EOFF);
    int* gecur = (int*)(ws + OFF_ECUR);
    int* list  = (int*)(ws + OFF_LIST);
    int* xl    = (int*)(ws + OFF_XL);
    int* xr    = (int*)(ws + OFF_XR);
    int* enc   = (int*)(ws + OFF_ENC);

    __shared__ int s_meta[NN];     // ll | lr<<4 | L<<8
    __shared__ int s_start[NN];
    __shared__ int s_seg[1024];
    __shared__ int s_un, s_nt;

    for (int j = t; j < MAXT; j += 1024) { gcnt[j] = 0; gcur[j] = 0; gecnt[j] = 0; gecur[j] = 0; }
    if (t == 0) s_nt = 0;
    for (int i = t; i < NN; i += 1024) {
        int ll = 1, lr = 1; bool has = false;
#pragma unroll
        for (int k = 0; k < KK; ++k) {
            if (lch[i * KK + k] >= 0) { ll = k + 2; has = true; }
            if (rch[i * KK + k] >= 0) { lr = k + 2; has = true; }
        }
        const int L = ll > lr ? ll : lr;
        s_meta[i]  = ll | (lr << 4) | (L << 8);
        s_start[i] = has ? -1 : 0;
    }
    __syncthreads();

    // fixpoint: start_j = max(0, max over child occ (c,k): start_c + L_c - k)
    for (;;) {
        if (t == 0) s_un = 0;
        __syncthreads();
        int myUn = 0;
        for (int i = t; i < NN; i += 1024) {
            if (s_start[i] < 0) {
                int mx = 0; bool ok = true;
#pragma unroll
                for (int k = 0; k < KK; ++k) {
                    int c = lch[i * KK + k];
                    if (c >= 0) {
                        const int st = s_start[c];
                        if (st < 0) ok = false;
                        else { const int v = st + ((s_meta[c] >> 8) & 0xF) - k; if (v > mx) mx = v; }
                    }
                    c = rch[i * KK + k];
                    if (c >= 0) {
                        const int st = s_start[c];
                        if (st < 0) ok = false;
                        else { const int v = st + ((s_meta[c] >> 8) & 0xF) - k; if (v > mx) mx = v; }
                    }
                }
                if (ok) s_start[i] = mx; else ++myUn;
            }
        }
        if (myUn) atomicAdd(&s_un, myUn);
        __syncthreads();
        if (s_un == 0) break;
        __syncthreads();
    }

    for (int i = t; i < NN; i += 1024)
        atomicMax(&s_nt, s_start[i] + ((s_meta[i] >> 8) & 0xF) + 1);
    __syncthreads();
    const int nt = s_nt;
    if (t == 0) hdr[0] = nt;
    for (int i = t; i < NN; i += 1024) {
        const int s = s_start[i], L = (s_meta[i] >> 8) & 0xF;
        for (int q = 0; q < L; ++q) atomicAdd(&gcnt[s + q], 1);
        atomicAdd(&gecnt[s + L], 1);
    }
    __syncthreads();

    auto scan4 = [&](int* cnt, int* off) {
        const int per = (nt + 1023) >> 10;
        const int lo = t * per, hi = (lo + per < nt) ? lo + per : nt;
        int sum = 0;
        for (int j = lo; j < hi; ++j) sum += (cnt[j] + 3) & ~3;
        s_seg[t] = sum;
        __syncthreads();
        if (t == 0) { int run = 0; for (int k = 0; k < 1024; ++k) { const int v = s_seg[k]; s_seg[k] = run; run += v; } }
        __syncthreads();
        int run = s_seg[t];
        for (int j = lo; j < hi; ++j) { off[j] = run; run += (cnt[j] + 3) & ~3; }
        __syncthreads();
    };
    scan4(gcnt, goff);
    scan4(gecnt, geoff);

    for (int i = t; i < NN; i += 1024) {
        const int m = s_meta[i], s = s_start[i];
        const int ll = m & 0xF, lr = (m >> 4) & 0xF, L = (m >> 8) & 0xF;
        for (int q = 0; q < L; ++q) {
            const int pos = goff[s + q] + atomicAdd(&gcur[s + q], 1);
            list[pos] = i | (q << 12) | (ll << 16) | (lr << 20);
            xl[pos] = (q == 0) ? i : ((q < ll) ? lch[i * KK + q - 1] : -1);
            xr[pos] = (q == 0) ? i : ((q < lr) ? rch[i * KK + q - 1] : -1);
        }
        const int ep = geoff[s + L] + atomicAdd(&gecur[s + L], 1);
        enc[ep] = i | (ll << 12) | (lr << 16);
    }
}

// ---------------------------------------------------------------------------
// Grid barrier (R4/R6..R9-proven): leader-gather + XCD-fanout, flags only,
// relaxed agent scope, no fences, poll backoff. SAFE ONLY at <=256 blocks,
// 1 block/CU (LDS > 80KB forces it at TPB=1024). UNCHANGED.
// ---------------------------------------------------------------------------
__device__ __forceinline__ void grid_barrier(int* ctrl, int blk, int xcd, int target) {
    __syncthreads();   // every wave: s_waitcnt vmcnt(0) before s_barrier
    if (blk == 0) {
        const int t = threadIdx.x;
        if (t < 64) {
            if (t == 0)
                __hip_atomic_store(ctrl + 0, target, __ATOMIC_RELAXED, __HIP_MEMORY_SCOPE_AGENT);
            int spin = 0;
            for (;;) {
                const int m0 = __hip_atomic_load(ctrl + t * 4 + 0, __ATOMIC_RELAXED, __HIP_MEMORY_SCOPE_AGENT);
                const int m1 = __hip_atomic_load(ctrl + t * 4 + 1, __ATOMIC_RELAXED, __HIP_MEMORY_SCOPE_AGENT);
                const int m2 = __hip_atomic_load(ctrl + t * 4 + 2, __ATOMIC_RELAXED, __HIP_MEMORY_SCOPE_AGENT);
                const int m3 = __hip_atomic_load(ctrl + t * 4 + 3, __ATOMIC_RELAXED, __HIP_MEMORY_SCOPE_AGENT);
                const bool ok = (m0 >= target) & (m1 >= target) & (m2 >= target) & (m3 >= target);
                if (__all(ok)) break;
                if (++spin > 64) __builtin_amdgcn_s_sleep(16);
                else             __builtin_amdgcn_s_sleep(1);
            }
            if (t < NXCD)
                __hip_atomic_store(ctrl + 512 + t * 16, target, __ATOMIC_RELAXED, __HIP_MEMORY_SCOPE_AGENT);
        }
    } else {
        if (threadIdx.x == 0) {
            __hip_atomic_store(ctrl + blk, target, __ATOMIC_RELAXED, __HIP_MEMORY_SCOPE_AGENT);
            int spin = 0;
            while (__hip_atomic_load(ctrl + 512 + xcd * 16, __ATOMIC_RELAXED, __HIP_MEMORY_SCOPE_AGENT) < target) {
                if (++spin > 64) __builtin_amdgcn_s_sleep(16);
                else             __builtin_amdgcn_s_sleep(1);
            }
        }
    }
    __syncthreads();
}

// R12 = R9 + register-free enc overlap:
//  (a) final substep (q == slen-1) stores hn INSTEAD of cn into cbuf — c is
//      dead after the chain, so cbuf[side][i] becomes a write-once final-h
//      row (cached-read-safe, see glds16 comment).
//  (b) at tick start, waves 0/1 glds16-stage slot0's final-h rows (both
//      sides) into s_eh[2][512] (4KB carved from pad; LDS stays 84.5KB >
//      80KB so 1 block/CU holds). Loads overlap substep staging + compute.
//  (c) one added uniform __syncthreads after the chunk loop publishes s_eh;
//      enc reduce reads LDS (~0.1us) instead of 8 serial MALL ldb2 (~0.9us).
//  Extra enc slots (ecnt > 8): old hbuf/ldb2 path, verbatim.
//  NO new register arrays (R11 spill lesson): WRITE_SIZE must stay ~1.4GB.
__global__ void __launch_bounds__(TPB, 1)
tree_lstm_kernel(const float* __restrict__ x0,
                 const float* __restrict__ Wl_ih, const float* __restrict__ Wl_hh,
                 const float* __restrict__ bl_ih, const float* __restrict__ bl_hh,
                 const float* __restrict__ Wr_ih, const float* __restrict__ Wr_hh,
                 const float* __restrict__ br_ih, const float* __restrict__ br_hh,
                 const float* __restrict__ W_enc, const float* __restrict__ b_enc,
                 float* ctx, char* ws) {
    const int tid  = threadIdx.x;
    const int wv   = tid >> 6;                 // wave index within block, 0..15
    const int wave = (blockIdx.x * TPB + tid) >> 6;  // 0..4095
    const int lane = tid & 63;
    const int u    = wave & 511;        // hidden unit owned by this wave
    const int side = (wave >> 9) & 1;   // 0 = left chain, 1 = right chain
    const int p    = (wave >> 10) & 3;  // 4-way slot split (uniform per block)
    const int egrp = (wave >> 9) & 7;   // enc: 8-way slot split (block-uniform)
    const int xcd  = blockIdx.x & (NXCD - 1);
    const int u0b  = (blockIdx.x * 16) & 511;  // block's first unit (16 contiguous)

    int*   ctrl  = (int*)(ws + OFF_CTRL);
    int*   hdr   = (int*)(ws + OFF_HDR);
    int*   gcnt  = (int*)(ws + OFF_TCNT);
    int*   goff  = (int*)(ws + OFF_TOFF);
    int*   gecnt = (int*)(ws + OFF_ECNT);
    int*   geoff = (int*)(ws + OFF_EOFF);
    int*   list  = (int*)(ws + OFF_LIST);
    int*   xlidx = (int*)(ws + OFF_XL);
    int*   xridx = (int*)(ws + OFF_XR);
    int*   encl  = (int*)(ws + OFF_ENC);
    float* hbuf  = (float*)(ws + OFF_H);
    float* cbuf  = (float*)(ws + OFF_C);

    // double-buffered row staging (x cached->LDS, h/c bypass->reg->LDS),
    // enc final-h staging, + pad (total ~84.5KB -> 1 block/CU guaranteed)
    __shared__ float s_x[2][8][512];
    __shared__ float s_h[2][8][512];
    __shared__ float s_c[2][8][16];
    __shared__ float s_eh[2][512];
    __shared__ float s_pad[4096];

    const float* Wih = side ? Wr_ih : Wl_ih;
    const float* Whh = side ? Wr_hh : Wl_hh;
    const float* bih = side ? br_ih : bl_ih;
    const float* bhh = side ? br_hh : bl_hh;

    // Wave-resident weights: 4 gate rows; lane l covers dims {4l..4l+3} and
    // {256+4l..256+4l+3} (dense 16B slices matching the LDS staging layout).
    v2f wih2[4][4], whh2[4][4];
#pragma unroll
    for (int g = 0; g < 4; ++g) {
        const size_t row = (size_t)g * HH + u;
        const float4 wa = *(const float4*)(Wih + row * DD + lane * 4);
        const float4 wb = *(const float4*)(Wih + row * DD + 256 + lane * 4);
        wih2[g][0] = (v2f){wa.x, wa.y}; wih2[g][1] = (v2f){wa.z, wa.w};
        wih2[g][2] = (v2f){wb.x, wb.y}; wih2[g][3] = (v2f){wb.z, wb.w};
        const float4 ha = *(const float4*)(Whh + row * HH + lane * 4);
        const float4 hb = *(const float4*)(Whh + row * HH + 256 + lane * 4);
        whh2[g][0] = (v2f){ha.x, ha.y}; whh2[g][1] = (v2f){ha.z, ha.w};
        whh2[g][2] = (v2f){hb.x, hb.y}; whh2[g][3] = (v2f){hb.z, hb.w};
    }
    const float bsumL = bih[(size_t)(lane & 3) * HH + u] + bhh[(size_t)(lane & 3) * HH + u];
    v2f wenc2[8];
#pragma unroll
    for (int j = 0; j < 4; ++j) {
        const float4 t = *(const float4*)(W_enc + (size_t)u * (2 * HH) + lane * 16 + j * 4);
        wenc2[j * 2 + 0] = (v2f){t.x, t.y};
        wenc2[j * 2 + 1] = (v2f){t.z, t.w};
    }
    const float bencv = b_enc[u];

    float* cb = cbuf + (size_t)side * NNHH;
    const int* xq = side ? xridx : xlidx;
    const int nt = hdr[0];
    if (nt < 0) ((volatile float*)s_pad)[tid] = 0.f;  // keep pad alive
    int bnum = 0;

    const int lhalf = lane >> 5;
    const int col   = (lane * 16) & 511;

    for (int tk = 0; tk < nt; ++tk) {
        const int cnt  = gcnt[tk],  off  = goff[tk];
        const int ecnt = gecnt[tk], eoff = geoff[tk];
        const int limit = off + cnt;
        const int elim  = eoff + ecnt;

        // ---- enc slot0 PRELOAD (register-free): stage both sides' final-h
        // rows (cbuf write-once aliasing) into s_eh via cached glds16 ----
        bool estaged = false;
        int  enode   = 0;
        if (ecnt > 0) {
            const int slot0 = eoff + egrp;
            if (slot0 < elim) {
                enode = encl[slot0] & 0xFFF;
                if (wv < 2) {
                    const float* r = cbuf + (size_t)wv * NNHH + (size_t)enode * HH + lane * 4;
                    glds16(r,       &s_eh[wv][0]);
                    glds16(r + 256, &s_eh[wv][256]);
                }
                estaged = true;
            }
        }

        // slot p owns positions {slotBase + 32c + j, j in [0,8)}
        const int slotBase = off + p * 8;
        const int nch = (limit > slotBase) ? ((limit - slotBase + 31) >> 5) : 0;

        // staging (waves 0-7): x rows cached glds16 -> LDS; h rows ldb2 ->
        // regs; c-segment on lanes 0-7. issue-early / write-late (R8-proven).
        v2f ph0, ph1, ph2, ph3, pc;
        bool pact = false;

        auto issue = [&](int buf, int chS) {
            pact = false;
            if (wv < 8) {
                const int e = chS + wv;
                if (e < limit) {
                    const int ent  = list[e];
                    const int q    = (ent >> 12) & 0xF;
                    const int xsrc = xq[e];
                    if (xsrc >= 0) {
                        const float* xrow = ((q == 0) ? x0 : ctx) + (size_t)xsrc * DD + lane * 4;
                        glds16(xrow,       &s_x[buf][wv][0]);
                        glds16(xrow + 256, &s_x[buf][wv][256]);
                        if (q > 0) {
                            pact = true;
                            const int i = ent & 0xFFF;
                            const float* hr = hbuf + (size_t)(((q & 1) ^ 1) * 2 + side) * NNHH
                                            + (size_t)i * HH + lane * 4;
                            ph0 = ldb2(hr);       ph1 = ldb2(hr + 2);
                            ph2 = ldb2(hr + 256); ph3 = ldb2(hr + 258);
                            if (lane < 8)
                                pc = ldb2(cb + (size_t)i * HH + u0b + lane * 2);
                        }
                    }
                }
            }
        };
        auto writeb = [&](int buf) {
            if (pact) {
                *(v2f*)&s_h[buf][wv][lane * 4]       = ph0;
                *(v2f*)&s_h[buf][wv][lane * 4 + 2]   = ph1;
                *(v2f*)&s_h[buf][wv][lane * 4 + 256] = ph2;
                *(v2f*)&s_h[buf][wv][lane * 4 + 258] = ph3;
                if (lane < 8)
                    *(v2f*)&s_c[buf][wv][lane * 2] = pc;
            }
        };

        if (nch > 0) { issue(0, slotBase); writeb(0); }
        for (int c = 0; c < nch; ++c) {
            __syncthreads();                    // buf[c&1] staged (all waves)
            const int chS = slotBase + (c << 5);
            if (c + 1 < nch) issue((c + 1) & 1, chS + 32);
            const int bb = c & 1;

            const int4 eA = *(const int4*)(list + chS);
            const int4 eB = *(const int4*)(list + chS + 4);
            const int4 cA = *(const int4*)(xq + chS);
            const int4 cB = *(const int4*)(xq + chS + 4);
            const int ei[8] = {eA.x, eA.y, eA.z, eA.w, eB.x, eB.y, eB.z, eB.w};
            const int ci[8] = {cA.x, cA.y, cA.z, cA.w, cB.x, cB.y, cB.z, cB.w};
            bool act[8];
#pragma unroll
            for (int j = 0; j < 8; ++j)
                act[j] = (chS + j < limit) && (ci[j] >= 0);

#pragma unroll
            for (int j = 0; j < 8; ++j) {
                if (!act[j]) continue;
                const int ent = ei[j];
                const int i   = ent & 0xFFF;
                const int qj  = (ent >> 12) & 0xF;
                const float cpj = (qj > 0) ? s_c[bb][j][wv] : 0.f;  // LDS broadcast
                const float4 xa = *(const float4*)&s_x[bb][j][lane * 4];
                const float4 xc = *(const float4*)&s_x[bb][j][lane * 4 + 256];
                v2f xv0 = (v2f){xa.x, xa.y}, xv1 = (v2f){xa.z, xa.w};
                v2f xv2 = (v2f){xc.x, xc.y}, xv3 = (v2f){xc.z, xc.w};
                v2f A0 = wih2[0][0] * xv0 + wih2[0][1] * xv1 + wih2[0][2] * xv2 + wih2[0][3] * xv3;
                v2f A1 = wih2[1][0] * xv0 + wih2[1][1] * xv1 + wih2[1][2] * xv2 + wih2[1][3] * xv3;
                v2f A2 = wih2[2][0] * xv0 + wih2[2][1] * xv1 + wih2[2][2] * xv2 + wih2[2][3] * xv3;
                v2f A3 = wih2[3][0] * xv0 + wih2[3][1] * xv1 + wih2[3][2] * xv2 + wih2[3][3] * xv3;
                if (qj > 0) {
                    const float4 ha = *(const float4*)&s_h[bb][j][lane * 4];
                    const float4 hc = *(const float4*)&s_h[bb][j][lane * 4 + 256];
                    v2f hv0 = (v2f){ha.x, ha.y}, hv1 = (v2f){ha.z, ha.w};
                    v2f hv2 = (v2f){hc.x, hc.y}, hv3 = (v2f){hc.z, hc.w};
                    A0 += whh2[0][0] * hv0 + whh2[0][1] * hv1 + whh2[0][2] * hv2 + whh2[0][3] * hv3;
                    A1 += whh2[1][0] * hv0 + whh2[1][1] * hv1 + whh2[1][2] * hv2 + whh2[1][3] * hv3;
                    A2 += whh2[2][0] * hv0 + whh2[2][1] * hv1 + whh2[2][2] * hv2 + whh2[2][3] * hv3;
                    A3 += whh2[3][0] * hv0 + whh2[3][1] * hv1 + whh2[3][2] * hv2 + whh2[3][3] * hv3;
                }
                float a0 = A0[0] + A0[1], a1 = A1[0] + A1[1];
                float a2 = A2[0] + A2[1], a3 = A3[0] + A3[1];
                // merge butterfly: lane l ends holding gate (l&3)'s sum
                float v01, v23, v;
                {
                    const bool hi = lane & 1;
                    float keep = hi ? a1 : a0, send = hi ? a0 : a1;
                    v01 = keep + __shfl_xor(send, 1, 64);
                    keep = hi ? a3 : a2; send = hi ? a2 : a3;
                    v23 = keep + __shfl_xor(send, 1, 64);
                }
                {
                    const bool hi = lane & 2;
                    const float keep = hi ? v23 : v01, send = hi ? v01 : v23;
                    v = keep + __shfl_xor(send, 2, 64);
                }
                v += __shfl_xor(v, 4, 64);
                v += __shfl_xor(v, 8, 64);
                v += __shfl_xor(v, 16, 64);
                v += __shfl_xor(v, 32, 64);
                // wave-parallel nonlinearities: sigm(x)=(tanh(x/2)+1)/2
                const float gate = v + bsumL;
                const bool  isG  = (lane & 3) == 2;
                const float th   = fast_tanh2x(isG ? (gate + gate) : gate);
                const float tl   = isG ? th : 0.5f * (th + 1.0f);
                const float ti = __shfl(tl, 0, 64);
                const float tf = __shfl(tl, 1, 64);
                const float tg = __shfl(tl, 2, 64);
                const float to = __shfl(tl, 3, 64);
                const float cn = tf * cpj + ti * tg;
                const float hn = to * fast_tanh2x(cn + cn);
                if (lane == 0) {
                    // final substep: store hn (final-h alias) — c is dead
                    const int slen = side ? ((ent >> 20) & 0xF) : ((ent >> 16) & 0xF);
                    coh_store(cb + (size_t)i * HH + u, (qj == slen - 1) ? hn : cn);
                    coh_store(hbuf + (size_t)((qj & 1) * 2 + side) * NNHH + (size_t)i * HH + u, hn);
                }
            }
            if (c + 1 < nch) writeb((c + 1) & 1);   // waits loads, LDS write
        }

        __syncthreads();   // publish s_eh (and uniform across block)

        // ---- enc FINISH: slot0 from LDS, extra slots via old ldb2 path ----
        if (ecnt > 0) {
            if (estaged) {
                const float* hv = &s_eh[lhalf][col];
                v2f acc2 = {0.f, 0.f};
#pragma unroll
                for (int k = 0; k < 8; ++k)
                    acc2 += wenc2[k] * *(const v2f*)(hv + k * 2);
                float acc = acc2[0] + acc2[1];
#pragma unroll
                for (int m = 1; m < 64; m <<= 1) acc += __shfl_xor(acc, m, 64);
                if (lane == 0)
                    coh_store(&ctx[(size_t)enode * DD + u], fast_tanh2x(2.0f * (acc + bencv)));
            }
            for (int slot = eoff + egrp + 8; slot < elim; slot += 8) {
                const int e   = encl[slot];
                const int i   = e & 0xFFF;
                const int len = (e >> (12 + 4 * lhalf)) & 0xF;
                const float* hv = hbuf + (size_t)(((len - 1) & 1) * 2 + lhalf) * NNHH
                                + (size_t)i * HH + col;
                v2f acc2 = {0.f, 0.f};
#pragma unroll
                for (int k = 0; k < 8; ++k)
                    acc2 += wenc2[k] * ldb2(hv + k * 2);
                float acc = acc2[0] + acc2[1];
#pragma unroll
                for (int m = 1; m < 64; m <<= 1) acc += __shfl_xor(acc, m, 64);
                if (lane == 0)
                    coh_store(&ctx[(size_t)i * DD + u], fast_tanh2x(2.0f * (acc + bencv)));
            }
        }
        grid_barrier(ctrl, blockIdx.x, xcd, ++bnum);
    }
}

extern "C" void kernel_launch(void* const* d_in, const int* in_sizes, int n_in,
                              void* d_out, int out_size, void* d_ws, size_t ws_size,
                              hipStream_t stream) {
    hipMemsetAsync(d_ws, 0, WS_ZERO_BYTES, stream);
    sched_kernel<<<dim3(1), dim3(1024), 0, stream>>>(
        (const int*)d_in[11], (const int*)d_in[12], (char*)d_ws);
    tree_lstm_kernel<<<dim3(NB), dim3(TPB), 0, stream>>>(
        (const float*)d_in[0],
        (const float*)d_in[1], (const float*)d_in[2],
        (const float*)d_in[3], (const float*)d_in[4],
        (const float*)d_in[5], (const float*)d_in[6],
        (const float*)d_in[7], (const float*)d_in[8],
        (const float*)d_in[9], (const float*)d_in[10],
        (float*)d_out, (char*)d_ws);
}